// Round 6
// baseline (993.376 us; speedup 1.0000x reference)
//
#include <hip/hip_runtime.h>
#include <hip/hip_bf16.h>

#define NB 16
#define NPTS 4096
#define DM 512
#define KTOP 64

typedef float f32x4 __attribute__((ext_vector_type(4)));
typedef short s16x8 __attribute__((ext_vector_type(8)));

__device__ __forceinline__ unsigned short f2bf(float x) {
    unsigned u = __builtin_bit_cast(unsigned, x);
    unsigned r = (u + 0x7FFFu + ((u >> 16) & 1u)) >> 16;   // RNE
    return (unsigned short)r;
}
__device__ __forceinline__ float bf2f(unsigned short h) {
    return __builtin_bit_cast(float, (unsigned)h << 16);
}

// dual split: x ~= hi + lo (for scale MLPs, ~2^-17 rel)
__device__ __forceinline__ void buildFragP(const float* ap, s16x8& hi, s16x8& lo) {
    float4 u0 = *(const float4*)ap;
    float4 u1 = *(const float4*)(ap + 4);
    float xs[8] = {u0.x, u0.y, u0.z, u0.w, u1.x, u1.y, u1.z, u1.w};
    #pragma unroll
    for (int j = 0; j < 8; j++) {
        unsigned short h = f2bf(xs[j]);
        hi[j] = (short)h;
        lo[j] = (short)f2bf(xs[j] - bf2f(h));
    }
}

// triple split: x ~= hi + mi + lo (for score MLP, ~2^-27 rel)
__device__ __forceinline__ void buildFrag3(const float* ap, s16x8& hi, s16x8& mi, s16x8& lo) {
    float4 u0 = *(const float4*)ap;
    float4 u1 = *(const float4*)(ap + 4);
    float xs[8] = {u0.x, u0.y, u0.z, u0.w, u1.x, u1.y, u1.z, u1.w};
    #pragma unroll
    for (int j = 0; j < 8; j++) {
        unsigned short h = f2bf(xs[j]);
        float r = xs[j] - bf2f(h);           // exact (Sterbenz)
        unsigned short m = f2bf(r);
        float r2 = r - bf2f(m);              // exact
        hi[j] = (short)h;
        mi[j] = (short)m;
        lo[j] = (short)f2bf(r2);
    }
}

// ---------------- Kernel 0a: weight prep — transpose + dual split (scale MLPs) ----------------
struct PD { const float* w; unsigned short* hi; unsigned short* lo; int K, N, kpad; };
struct PA9 { PD d[9]; };

__global__ __launch_bounds__(256) void k_prep(PA9 p) {
    PD d = p.d[blockIdx.y];
    int total = d.N * d.kpad;
    for (int i = blockIdx.x * 256 + threadIdx.x; i < total; i += gridDim.x * 256) {
        int n = i / d.kpad, k = i - n * d.kpad;
        float x = (k < d.K) ? d.w[(long)k * d.N + n] : 0.f;
        unsigned short h = f2bf(x);
        d.hi[(long)n * d.kpad + k] = h;
        d.lo[(long)n * d.kpad + k] = f2bf(x - bf2f(h));
    }
}

// ---------------- Kernel 0b: weight prep — transpose + TRIPLE split (score MLP) ----------------
struct PD3 { const float* w; unsigned short* hi; unsigned short* mi; unsigned short* lo; int K, N, kpad; };
struct PA2 { PD3 d[2]; };

__global__ __launch_bounds__(256) void k_prep3(PA2 p) {
    PD3 d = p.d[blockIdx.y];
    int total = d.N * d.kpad;
    for (int i = blockIdx.x * 256 + threadIdx.x; i < total; i += gridDim.x * 256) {
        int n = i / d.kpad, k = i - n * d.kpad;
        float x = (k < d.K) ? d.w[(long)k * d.N + n] : 0.f;
        unsigned short h = f2bf(x);
        float r = x - bf2f(h);
        unsigned short m = f2bf(r);
        float r2 = r - bf2f(m);
        d.hi[(long)n * d.kpad + k] = h;
        d.mi[(long)n * d.kpad + k] = m;
        d.lo[(long)n * d.kpad + k] = f2bf(r2);
    }
}

// ---------------- Kernel 1 (MFMA): score MLP 512->256->64->1, TRIPLE-split bf16 x6 ----------------
// err ~1e-7 per score — below f32 accumulation-order noise; safe for top-k ranking.
__global__ __launch_bounds__(256) void k_score_mfma(
    const float* __restrict__ feat,
    const unsigned short* __restrict__ wh0, const unsigned short* __restrict__ wm0,
    const unsigned short* __restrict__ wl0,
    const unsigned short* __restrict__ wh1, const unsigned short* __restrict__ wm1,
    const unsigned short* __restrict__ wl1,
    const float* __restrict__ b0, const float* __restrict__ b1,
    const float* __restrict__ w2, const float* __restrict__ b2,
    float* __restrict__ score)
{
    __shared__ float h1s[64 * 260];          // layer-1 output; h2[64][68] overlays later
    const int tid = threadIdx.x;
    const int lane = tid & 63, w = tid >> 6;
    const int q = lane >> 4, ln = lane & 15;
    const long p0 = (long)blockIdx.x * 64;

    const float* arow = feat + (p0 + 16 * w + ln) * 512;

    // ===== layer 1: K=512, N=256 =====
    f32x4 acc1[16];
    #pragma unroll
    for (int t = 0; t < 16; t++) acc1[t] = (f32x4){0.f, 0.f, 0.f, 0.f};

    for (int kc = 0; kc < 16; kc++) {
        s16x8 ah, am, al;
        buildFrag3(arow + kc * 32 + q * 8, ah, am, al);
        const int kof = kc * 32 + q * 8;
        #pragma unroll
        for (int ct = 0; ct < 16; ct++) {
            long wb = (long)(ct * 16 + ln) * 512 + kof;
            s16x8 bh = *(const s16x8*)(wh0 + wb);
            s16x8 bm = *(const s16x8*)(wm0 + wb);
            s16x8 bl = *(const s16x8*)(wl0 + wb);
            acc1[ct] = __builtin_amdgcn_mfma_f32_16x16x32_bf16(ah, bl, acc1[ct], 0, 0, 0);
            acc1[ct] = __builtin_amdgcn_mfma_f32_16x16x32_bf16(al, bh, acc1[ct], 0, 0, 0);
            acc1[ct] = __builtin_amdgcn_mfma_f32_16x16x32_bf16(am, bm, acc1[ct], 0, 0, 0);
            acc1[ct] = __builtin_amdgcn_mfma_f32_16x16x32_bf16(ah, bm, acc1[ct], 0, 0, 0);
            acc1[ct] = __builtin_amdgcn_mfma_f32_16x16x32_bf16(am, bh, acc1[ct], 0, 0, 0);
            acc1[ct] = __builtin_amdgcn_mfma_f32_16x16x32_bf16(ah, bh, acc1[ct], 0, 0, 0);
        }
    }
    #pragma unroll
    for (int ct = 0; ct < 16; ct++) {
        float bias = b0[ct * 16 + ln];
        #pragma unroll
        for (int r = 0; r < 4; r++)
            h1s[(16 * w + 4 * q + r) * 260 + ct * 16 + ln] = fmaxf(acc1[ct][r] + bias, 0.f);
    }
    __syncthreads();

    // ===== layer 2: K=256, N=64 =====
    f32x4 acc2[4];
    #pragma unroll
    for (int t = 0; t < 4; t++) acc2[t] = (f32x4){0.f, 0.f, 0.f, 0.f};

    for (int kc = 0; kc < 8; kc++) {
        s16x8 ah, am, al;
        buildFrag3(&h1s[(16 * w + ln) * 260 + kc * 32 + q * 8], ah, am, al);
        const int kof = kc * 32 + q * 8;
        #pragma unroll
        for (int ct = 0; ct < 4; ct++) {
            long wb = (long)(ct * 16 + ln) * 256 + kof;
            s16x8 bh = *(const s16x8*)(wh1 + wb);
            s16x8 bm = *(const s16x8*)(wm1 + wb);
            s16x8 bl = *(const s16x8*)(wl1 + wb);
            acc2[ct] = __builtin_amdgcn_mfma_f32_16x16x32_bf16(ah, bl, acc2[ct], 0, 0, 0);
            acc2[ct] = __builtin_amdgcn_mfma_f32_16x16x32_bf16(al, bh, acc2[ct], 0, 0, 0);
            acc2[ct] = __builtin_amdgcn_mfma_f32_16x16x32_bf16(am, bm, acc2[ct], 0, 0, 0);
            acc2[ct] = __builtin_amdgcn_mfma_f32_16x16x32_bf16(ah, bm, acc2[ct], 0, 0, 0);
            acc2[ct] = __builtin_amdgcn_mfma_f32_16x16x32_bf16(am, bh, acc2[ct], 0, 0, 0);
            acc2[ct] = __builtin_amdgcn_mfma_f32_16x16x32_bf16(ah, bh, acc2[ct], 0, 0, 0);
        }
    }
    __syncthreads();                          // all reads of h1s done before overlay
    float* h2 = h1s;                          // [64][68]
    #pragma unroll
    for (int ct = 0; ct < 4; ct++) {
        float bias = b1[ct * 16 + ln];
        #pragma unroll
        for (int r = 0; r < 4; r++)
            h2[(16 * w + 4 * q + r) * 68 + ct * 16 + ln] = fmaxf(acc2[ct][r] + bias, 0.f);
    }
    __syncthreads();

    // ===== layer 3: scalar (no relu), exact f32 =====
    {
        int m = tid >> 2, seg = tid & 3;
        float acc = 0.f;
        #pragma unroll
        for (int i = 0; i < 16; i++) acc += h2[m * 68 + seg * 16 + i] * w2[seg * 16 + i];
        acc += __shfl_xor(acc, 1);
        acc += __shfl_xor(acc, 2);
        if (seg == 0) score[p0 + m] = acc + b2[0];
    }
}

// ---------------- (fallback) old score MLP ----------------
__global__ __launch_bounds__(256) void k_score(
    const float* __restrict__ feat,
    const float* __restrict__ w0, const float* __restrict__ b0,
    const float* __restrict__ w1, const float* __restrict__ b1,
    const float* __restrict__ w2, const float* __restrict__ b2,
    float* __restrict__ score)
{
    __shared__ float fbuf[16][512];
    __shared__ float h1[16][256];
    __shared__ float h2[16][64];
    const int tid = threadIdx.x;
    const long p0 = (long)blockIdx.x * 16;

    for (int e = tid; e < 16 * 512; e += 256) {
        int m = e >> 9, i = e & 511;
        fbuf[m][i] = feat[(p0 + m) * 512 + i];
    }
    __syncthreads();
    {
        const int o = tid;
        float acc[16];
        const float bb = b0[o];
        #pragma unroll
        for (int m = 0; m < 16; m++) acc[m] = bb;
        for (int i = 0; i < 512; i++) {
            float w = w0[i * 256 + o];
            #pragma unroll
            for (int m = 0; m < 16; m++) acc[m] += fbuf[m][i] * w;
        }
        #pragma unroll
        for (int m = 0; m < 16; m++) h1[m][o] = fmaxf(acc[m], 0.f);
    }
    __syncthreads();
    {
        const int o = tid & 63, g = tid >> 6;
        float acc[4];
        const float bb = b1[o];
        #pragma unroll
        for (int mm = 0; mm < 4; mm++) acc[mm] = bb;
        for (int i = 0; i < 256; i++) {
            float w = w1[i * 64 + o];
            #pragma unroll
            for (int mm = 0; mm < 4; mm++) acc[mm] += h1[g * 4 + mm][i] * w;
        }
        #pragma unroll
        for (int mm = 0; mm < 4; mm++) h2[g * 4 + mm][o] = fmaxf(acc[mm], 0.f);
    }
    __syncthreads();
    if (tid < 16) {
        float acc = b2[0];
        for (int i = 0; i < 64; i++) acc += h2[tid][i] * w2[i];
        score[p0 + tid] = acc;
    }
}

// ---------------- Kernel 2: top-64 per batch (desc, ties -> lower idx) ----------------
__global__ __launch_bounds__(256) void k_topk(const float* __restrict__ score,
                                              int* __restrict__ topk)
{
    __shared__ float sc[4096];
    __shared__ float wv[4];
    __shared__ int   wi[4];
    const int b = blockIdx.x, tid = threadIdx.x;
    const int lane = tid & 63, w = tid >> 6;
    for (int e = tid; e < 4096; e += 256) sc[e] = score[b * 4096 + e];
    __syncthreads();
    for (int it = 0; it < KTOP; it++) {
        float bv = -INFINITY; int bi = 1 << 30;
        #pragma unroll
        for (int j = 0; j < 16; j++) {
            int e = tid + 256 * j;
            float v = sc[e];
            if (v > bv || (v == bv && e < bi)) { bv = v; bi = e; }
        }
        #pragma unroll
        for (int s = 1; s < 64; s <<= 1) {
            float ov = __shfl_xor(bv, s);
            int   oi = __shfl_xor(bi, s);
            if (ov > bv || (ov == bv && oi < bi)) { bv = ov; bi = oi; }
        }
        if (lane == 0) { wv[w] = bv; wi[w] = bi; }
        __syncthreads();
        if (tid == 0) {
            float v = wv[0]; int i = wi[0];
            #pragma unroll
            for (int k = 1; k < 4; k++)
                if (wv[k] > v || (wv[k] == v && wi[k] < i)) { v = wv[k]; i = wi[k]; }
            topk[b * KTOP + it] = i;
            sc[i] = -INFINITY;
        }
        __syncthreads();
    }
}

// ---------------- Kernel 3: ball grouping (1 wave per (b,s)) ----------------
__global__ __launch_bounds__(64) void k_ball(
    const float* __restrict__ points, const int* __restrict__ topk,
    int* __restrict__ idx0, int* __restrict__ idx1, int* __restrict__ idx2)
{
    const int bs = blockIdx.x;
    const int b = bs >> 6;
    const int lane = threadIdx.x;
    const int j0 = topk[bs];
    const float* pb = points + (long)b * NPTS * 6;
    const float qx = pb[(long)j0 * 6 + 0];
    const float qy = pb[(long)j0 * 6 + 1];
    const float qz = pb[(long)j0 * 6 + 2];
    const float r2s[3] = {0.01f, 0.04f, 0.16f};
    const int ns[3] = {16, 32, 128};
    int cnt[3] = {0, 0, 0};
    int firstj[3] = {0, 0, 0};
    int* lists[3] = {idx0 + bs * 16, idx1 + bs * 32, idx2 + bs * 128};

    for (int c = 0; c < NPTS / 64; c++) {
        int j = c * 64 + lane;
        float px = pb[(long)j * 6 + 0];
        float py = pb[(long)j * 6 + 1];
        float pz = pb[(long)j * 6 + 2];
        float dx = __fsub_rn(qx, px), dy = __fsub_rn(qy, py), dz = __fsub_rn(qz, pz);
        float d2 = __fadd_rn(__fadd_rn(__fmul_rn(dx, dx), __fmul_rn(dy, dy)), __fmul_rn(dz, dz));
        #pragma unroll
        for (int r = 0; r < 3; r++) {
            bool inr = d2 <= r2s[r];
            unsigned long long m = __ballot(inr);
            if (m == 0ULL) continue;
            if (cnt[r] == 0) firstj[r] = c * 64 + (__ffsll((unsigned long long)m) - 1);
            if (cnt[r] < ns[r] && inr) {
                int pos = cnt[r] + __popcll(m & ((1ULL << lane) - 1ULL));
                if (pos < ns[r]) lists[r][pos] = j;
            }
            cnt[r] += __popcll(m);
        }
    }
    #pragma unroll
    for (int r = 0; r < 3; r++) {
        int filled = cnt[r] < ns[r] ? cnt[r] : ns[r];
        for (int p = filled + lane; p < ns[r]; p += 64) lists[r][p] = firstj[r];
    }
}

// ---------------- Kernel 4 (MFMA): per-scale grouped MLP + max, dual-split bf16 x3 ----------------
template<int NS, int C1, int C2, int C3>
__global__ __launch_bounds__(256) void k_scale_mfma(
    const float* __restrict__ feat, const float* __restrict__ points,
    const int* __restrict__ topk, const int* __restrict__ idxlist,
    const unsigned short* __restrict__ wh0, const unsigned short* __restrict__ wl0,
    const unsigned short* __restrict__ wh1, const unsigned short* __restrict__ wl1,
    const unsigned short* __restrict__ wh2, const unsigned short* __restrict__ wl2,
    const float* __restrict__ b0, const float* __restrict__ b1, const float* __restrict__ b2,
    float* __restrict__ pA, float* __restrict__ pB, int colOff)
{
    constexpr int KP1 = 544;
    constexpr int CMAX = C3;
    constexpr int SA = 100, SB = 72, SW = 40;
    __shared__ float bufA[64 * SA];
    __shared__ float bufB[64 * SB];
    __shared__ unsigned short wHi[CMAX * SW];
    __shared__ unsigned short wLo[CMAX * SW];

    const int tid = threadIdx.x;
    const int lane = tid & 63, w = tid >> 6;
    const int q = lane >> 4, ln = lane & 15;
    const int bblk = ((blockIdx.x * 64) / NS) >> 6;

    int* row_j = (int*)bufB;
    float* qv = bufB + 64;

    if (tid < 64) {
        int P = blockIdx.x * 64 + tid;
        int g = P / NS;
        int j = idxlist[P];
        row_j[tid] = j;
        int j0 = topk[g];
        const float* pp = points + ((long)bblk * NPTS + j0) * 6;
        qv[tid * 3 + 0] = pp[0];
        qv[tid * 3 + 1] = pp[1];
        qv[tid * 3 + 2] = pp[2];
    }
    __syncthreads();

    const float* fbase = feat + (long)bblk * NPTS * 512;
    const float* pbase = points + (long)bblk * NPTS * 6;

    // ===== layer 1: K=515(pad544), N=C1 =====
    f32x4 acc1[C1 / 16];
    #pragma unroll
    for (int t = 0; t < C1 / 16; t++) acc1[t] = (f32x4){0.f, 0.f, 0.f, 0.f};

    for (int kc = 0; kc < KP1 / 32; kc++) {
        {
            int row = tid >> 2, seg = tid & 3;
            int j = row_j[row];
            float4 v0, v1;
            if (kc < 16) {
                const float* src = fbase + (long)j * 512 + kc * 32 + seg * 8;
                v0 = *(const float4*)src;
                v1 = *(const float4*)(src + 4);
            } else {
                v0 = make_float4(0.f, 0.f, 0.f, 0.f);
                v1 = make_float4(0.f, 0.f, 0.f, 0.f);
                if (seg == 0) {
                    const float* pj = pbase + (long)j * 6;
                    v0.x = __fsub_rn(pj[0], qv[row * 3 + 0]);
                    v0.y = __fsub_rn(pj[1], qv[row * 3 + 1]);
                    v0.z = __fsub_rn(pj[2], qv[row * 3 + 2]);
                }
            }
            *(float4*)&bufA[row * SA + seg * 8] = v0;
            *(float4*)&bufA[row * SA + seg * 8 + 4] = v1;
        }
        for (int i = tid; i < C1 * 4; i += 256) {
            int n = i >> 2, seg = i & 3;
            long off = (long)n * KP1 + kc * 32 + seg * 8;
            *(float4*)&wHi[n * SW + seg * 8] = *(const float4*)(wh0 + off);
            *(float4*)&wLo[n * SW + seg * 8] = *(const float4*)(wl0 + off);
        }
        __syncthreads();

        s16x8 ahi, alo;
        buildFragP(&bufA[(16 * w + ln) * SA + q * 8], ahi, alo);
        #pragma unroll
        for (int ct = 0; ct < C1 / 16; ct++) {
            s16x8 bhi = *(const s16x8*)&wHi[(ct * 16 + ln) * SW + q * 8];
            s16x8 blo = *(const s16x8*)&wLo[(ct * 16 + ln) * SW + q * 8];
            acc1[ct] = __builtin_amdgcn_mfma_f32_16x16x32_bf16(ahi, bhi, acc1[ct], 0, 0, 0);
            acc1[ct] = __builtin_amdgcn_mfma_f32_16x16x32_bf16(ahi, blo, acc1[ct], 0, 0, 0);
            acc1[ct] = __builtin_amdgcn_mfma_f32_16x16x32_bf16(alo, bhi, acc1[ct], 0, 0, 0);
        }
        __syncthreads();
    }
    #pragma unroll
    for (int ct = 0; ct < C1 / 16; ct++) {
        float bias = b0[ct * 16 + ln];
        #pragma unroll
        for (int r = 0; r < 4; r++) {
            float v = fmaxf(acc1[ct][r] + bias, 0.f);
            bufB[(16 * w + 4 * q + r) * SB + ct * 16 + ln] = v;
        }
    }
    __syncthreads();

    // ===== layer 2: K=C1, N=C2 =====
    f32x4 acc2[C2 / 16];
    #pragma unroll
    for (int t = 0; t < C2 / 16; t++) acc2[t] = (f32x4){0.f, 0.f, 0.f, 0.f};

    for (int kc = 0; kc < C1 / 32; kc++) {
        for (int i = tid; i < C2 * 4; i += 256) {
            int n = i >> 2, seg = i & 3;
            long off = (long)n * C1 + kc * 32 + seg * 8;
            *(float4*)&wHi[n * SW + seg * 8] = *(const float4*)(wh1 + off);
            *(float4*)&wLo[n * SW + seg * 8] = *(const float4*)(wl1 + off);
        }
        __syncthreads();
        s16x8 ahi, alo;
        buildFragP(&bufB[(16 * w + ln) * SB + kc * 32 + q * 8], ahi, alo);
        #pragma unroll
        for (int ct = 0; ct < C2 / 16; ct++) {
            s16x8 bhi = *(const s16x8*)&wHi[(ct * 16 + ln) * SW + q * 8];
            s16x8 blo = *(const s16x8*)&wLo[(ct * 16 + ln) * SW + q * 8];
            acc2[ct] = __builtin_amdgcn_mfma_f32_16x16x32_bf16(ahi, bhi, acc2[ct], 0, 0, 0);
            acc2[ct] = __builtin_amdgcn_mfma_f32_16x16x32_bf16(ahi, blo, acc2[ct], 0, 0, 0);
            acc2[ct] = __builtin_amdgcn_mfma_f32_16x16x32_bf16(alo, bhi, acc2[ct], 0, 0, 0);
        }
        __syncthreads();
    }
    #pragma unroll
    for (int ct = 0; ct < C2 / 16; ct++) {
        float bias = b1[ct * 16 + ln];
        #pragma unroll
        for (int r = 0; r < 4; r++) {
            float v = fmaxf(acc2[ct][r] + bias, 0.f);
            bufA[(16 * w + 4 * q + r) * SA + ct * 16 + ln] = v;
        }
    }
    __syncthreads();

    // ===== layer 3: K=C2, N=C3 =====
    f32x4 acc3[C3 / 16];
    #pragma unroll
    for (int t = 0; t < C3 / 16; t++) acc3[t] = (f32x4){0.f, 0.f, 0.f, 0.f};

    for (int kc = 0; kc < C2 / 32; kc++) {
        for (int i = tid; i < C3 * 4; i += 256) {
            int n = i >> 2, seg = i & 3;
            long off = (long)n * C2 + kc * 32 + seg * 8;
            *(float4*)&wHi[n * SW + seg * 8] = *(const float4*)(wh2 + off);
            *(float4*)&wLo[n * SW + seg * 8] = *(const float4*)(wl2 + off);
        }
        __syncthreads();
        s16x8 ahi, alo;
        buildFragP(&bufA[(16 * w + ln) * SA + kc * 32 + q * 8], ahi, alo);
        #pragma unroll
        for (int ct = 0; ct < C3 / 16; ct++) {
            s16x8 bhi = *(const s16x8*)&wHi[(ct * 16 + ln) * SW + q * 8];
            s16x8 blo = *(const s16x8*)&wLo[(ct * 16 + ln) * SW + q * 8];
            acc3[ct] = __builtin_amdgcn_mfma_f32_16x16x32_bf16(ahi, bhi, acc3[ct], 0, 0, 0);
            acc3[ct] = __builtin_amdgcn_mfma_f32_16x16x32_bf16(ahi, blo, acc3[ct], 0, 0, 0);
            acc3[ct] = __builtin_amdgcn_mfma_f32_16x16x32_bf16(alo, bhi, acc3[ct], 0, 0, 0);
        }
        __syncthreads();
    }
    float* part = bufB;
    #pragma unroll
    for (int ct = 0; ct < C3 / 16; ct++) {
        float bias = b2[ct * 16 + ln];
        float v = -INFINITY;
        #pragma unroll
        for (int r = 0; r < 4; r++) v = fmaxf(v, fmaxf(acc3[ct][r] + bias, 0.f));
        v = fmaxf(v, __shfl_xor(v, 16));
        v = fmaxf(v, __shfl_xor(v, 32));
        if (lane < 16) part[w * C3 + ct * 16 + lane] = v;
    }
    __syncthreads();

    constexpr int NSB = NS < 64 ? NS : 64;
    constexpr int WPG = NSB / 16;
    constexpr int NOG = 4 / WPG;
    if (tid < NOG * C3) {
        int o = tid / C3, c = tid - o * C3;
        float v = part[(o * WPG) * C3 + c];
        #pragma unroll
        for (int i = 1; i < WPG; i++) v = fmaxf(v, part[(o * WPG + i) * C3 + c]);
        int g = (blockIdx.x * 64) / NS + o;
        if (NS <= 64) {
            pA[g * 320 + colOff + c] = v;
        } else {
            if ((blockIdx.x & 1) == 0) pA[g * 320 + colOff + c] = v;
            else pB[g * 128 + c] = v;
        }
    }
}

// ---------------- (fallback) old per-scale MLP ----------------
__global__ __launch_bounds__(256) void k_scale(
    const float* __restrict__ feat, const float* __restrict__ points,
    const int* __restrict__ topk, const int* __restrict__ idxlist, int ns,
    const float* __restrict__ w0, const float* __restrict__ b0, int C1,
    const float* __restrict__ w1, const float* __restrict__ b1, int C2,
    const float* __restrict__ w2, const float* __restrict__ b2, int C3,
    float* __restrict__ feat_abs, int colOff)
{
    __shared__ float g[2][520];
    __shared__ float h1[2][128];
    __shared__ float h2[2][128];
    const int bs = blockIdx.x;
    const int b = bs >> 6;
    const int tid = threadIdx.x;
    const int ks = tid >> 7;
    const int c = tid & 127;
    const int j0 = topk[bs];
    const float* pb = points + (long)b * NPTS * 6;
    const float* fb = feat + (long)b * NPTS * 512;
    const float q0 = pb[(long)j0 * 6 + 0];
    const float q1 = pb[(long)j0 * 6 + 1];
    const float q2 = pb[(long)j0 * 6 + 2];
    float omax = -INFINITY;
    const int* il = idxlist + bs * ns;

    for (int k0 = 0; k0 < ns; k0 += 2) {
        for (int kk = 0; kk < 2; kk++) {
            int j = il[k0 + kk];
            for (int e = tid; e < 512; e += 256) g[kk][e] = fb[(long)j * 512 + e];
            if (tid == 0) {
                g[kk][512] = __fsub_rn(pb[(long)j * 6 + 0], q0);
                g[kk][513] = __fsub_rn(pb[(long)j * 6 + 1], q1);
                g[kk][514] = __fsub_rn(pb[(long)j * 6 + 2], q2);
            }
        }
        __syncthreads();
        if (c < C1) {
            float acc = b0[c];
            for (int i = 0; i < 515; i++) acc += g[ks][i] * w0[i * C1 + c];
            h1[ks][c] = fmaxf(acc, 0.f);
        }
        __syncthreads();
        if (c < C2) {
            float acc = b1[c];
            for (int i = 0; i < C1; i++) acc += h1[ks][i] * w1[i * C2 + c];
            h2[ks][c] = fmaxf(acc, 0.f);
        }
        __syncthreads();
        if (c < C3) {
            float acc = b2[c];
            for (int i = 0; i < C2; i++) acc += h2[ks][i] * w2[i * C3 + c];
            omax = fmaxf(omax, fmaxf(acc, 0.f));
        }
        __syncthreads();
    }
    if (ks == 1 && c < C3) h1[0][c] = omax;
    __syncthreads();
    if (ks == 0 && c < C3)
        feat_abs[bs * 320 + colOff + c] = fmaxf(omax, h1[0][c]);
}

// ---------------- Kernel 5: agg MLP 320->256->256->505 + concat ----------------
__global__ __launch_bounds__(256) void k_agg(
    const float* __restrict__ feat_abs, const float* __restrict__ pB, int usePB,
    const float* __restrict__ score,
    const int* __restrict__ topk, const float* __restrict__ points,
    const float* __restrict__ w0, const float* __restrict__ b0,
    const float* __restrict__ w1, const float* __restrict__ b1,
    const float* __restrict__ w2, const float* __restrict__ b2,
    float* __restrict__ out)
{
    __shared__ float x[320];
    __shared__ float h1[256];
    __shared__ float h2[256];
    const int bs = blockIdx.x, tid = threadIdx.x;
    const int b = bs >> 6;
    for (int e = tid; e < 320; e += 256) {
        float v = feat_abs[bs * 320 + e];
        if (usePB && e >= 192) v = fmaxf(v, pB[bs * 128 + (e - 192)]);
        x[e] = v;
    }
    __syncthreads();
    {
        float acc = b0[tid];
        for (int i = 0; i < 320; i++) acc += x[i] * w0[i * 256 + tid];
        h1[tid] = fmaxf(acc, 0.f);
    }
    __syncthreads();
    {
        float acc = b1[tid];
        for (int i = 0; i < 256; i++) acc += h1[i] * w1[i * 256 + tid];
        h2[tid] = fmaxf(acc, 0.f);
    }
    __syncthreads();
    float* orow = out + (long)bs * 512;
    for (int o = tid; o < 505; o += 256) {
        float acc = b2[o];
        for (int i = 0; i < 256; i++) acc += h2[i] * w2[i * 505 + o];
        orow[o] = acc;
    }
    if (tid == 0) {
        int j = topk[bs];
        orow[505] = score[b * 4096 + j];
        #pragma unroll
        for (int d = 0; d < 6; d++) orow[506 + d] = points[((long)b * NPTS + j) * 6 + d];
    }
}

extern "C" void kernel_launch(void* const* d_in, const int* in_sizes, int n_in,
                              void* d_out, int out_size, void* d_ws, size_t ws_size,
                              hipStream_t stream)
{
    const float* points = (const float*)d_in[0];
    const float* feat   = (const float*)d_in[1];
    const float* fc_w0 = (const float*)d_in[2];  const float* fc_b0 = (const float*)d_in[3];
    const float* fc_w1 = (const float*)d_in[4];  const float* fc_b1 = (const float*)d_in[5];
    const float* fc_w2 = (const float*)d_in[6];  const float* fc_b2 = (const float*)d_in[7];
    const float* s0_w0 = (const float*)d_in[8];  const float* s0_b0 = (const float*)d_in[9];
    const float* s0_w1 = (const float*)d_in[10]; const float* s0_b1 = (const float*)d_in[11];
    const float* s0_w2 = (const float*)d_in[12]; const float* s0_b2 = (const float*)d_in[13];
    const float* s1_w0 = (const float*)d_in[14]; const float* s1_b0 = (const float*)d_in[15];
    const float* s1_w1 = (const float*)d_in[16]; const float* s1_b1 = (const float*)d_in[17];
    const float* s1_w2 = (const float*)d_in[18]; const float* s1_b2 = (const float*)d_in[19];
    const float* s2_w0 = (const float*)d_in[20]; const float* s2_b0 = (const float*)d_in[21];
    const float* s2_w1 = (const float*)d_in[22]; const float* s2_b1 = (const float*)d_in[23];
    const float* s2_w2 = (const float*)d_in[24]; const float* s2_b2 = (const float*)d_in[25];
    const float* ag_w0 = (const float*)d_in[26]; const float* ag_b0 = (const float*)d_in[27];
    const float* ag_w1 = (const float*)d_in[28]; const float* ag_b1 = (const float*)d_in[29];
    const float* ag_w2 = (const float*)d_in[30]; const float* ag_b2 = (const float*)d_in[31];

    char* ws = (char*)d_ws;
    float* score    = (float*)(ws + 0);
    int*   topk     = (int*)  (ws + 262144);
    int*   idx0     = (int*)  (ws + 266240);
    int*   idx1     = (int*)  (ws + 331776);
    int*   idx2     = (int*)  (ws + 462848);
    float* feat_abs = (float*)(ws + 987136);          // pA [1024][320]
    float* pB       = (float*)(ws + 2297856);         // [1024][128]
    size_t cur = 2822144;
    auto alloc = [&](size_t bytes) { size_t o = cur; cur = (cur + bytes + 255) & ~(size_t)255; return o; };

    const int Cs[3][3] = {{32, 32, 64}, {64, 64, 128}, {64, 96, 128}};
    const float* Wsrc[3][3] = {{s0_w0, s0_w1, s0_w2}, {s1_w0, s1_w1, s1_w2}, {s2_w0, s2_w1, s2_w2}};
    unsigned short* whi[3][3]; unsigned short* wlo[3][3];
    PA9 pargs;
    int di = 0;
    for (int s = 0; s < 3; s++) {
        int Ks[3] = {515, Cs[s][0], Cs[s][1]};
        int Kp[3] = {544, Cs[s][0], Cs[s][1]};
        for (int l = 0; l < 3; l++) {
            int N = Cs[s][l];
            size_t bytes = (size_t)N * Kp[l] * 2;
            whi[s][l] = (unsigned short*)(ws + alloc(bytes));
            wlo[s][l] = (unsigned short*)(ws + alloc(bytes));
            pargs.d[di++] = {Wsrc[s][l], whi[s][l], wlo[s][l], Ks[l], N, Kp[l]};
        }
    }
    // fc weights (triple split): fc_w0 [512][256] kpad=512, fc_w1 [256][64] kpad=256
    unsigned short* fhi0 = (unsigned short*)(ws + alloc((size_t)256 * 512 * 2));
    unsigned short* fmi0 = (unsigned short*)(ws + alloc((size_t)256 * 512 * 2));
    unsigned short* flo0 = (unsigned short*)(ws + alloc((size_t)256 * 512 * 2));
    unsigned short* fhi1 = (unsigned short*)(ws + alloc((size_t)64 * 256 * 2));
    unsigned short* fmi1 = (unsigned short*)(ws + alloc((size_t)64 * 256 * 2));
    unsigned short* flo1 = (unsigned short*)(ws + alloc((size_t)64 * 256 * 2));
    PA2 pargs3;
    pargs3.d[0] = {fc_w0, fhi0, fmi0, flo0, 512, 256, 512};
    pargs3.d[1] = {fc_w1, fhi1, fmi1, flo1, 256, 64, 256};

    bool mfma_ok = (ws_size >= cur);

    if (mfma_ok) {
        k_prep<<<dim3(136, 9), 256, 0, stream>>>(pargs);
        k_prep3<<<dim3(512, 2), 256, 0, stream>>>(pargs3);
        k_score_mfma<<<1024, 256, 0, stream>>>(feat, fhi0, fmi0, flo0, fhi1, fmi1, flo1,
            fc_b0, fc_b1, fc_w2, fc_b2, score);
    } else {
        k_score<<<4096, 256, 0, stream>>>(feat, fc_w0, fc_b0, fc_w1, fc_b1, fc_w2, fc_b2, score);
    }
    k_topk<<<NB, 256, 0, stream>>>(score, topk);
    k_ball<<<NB * KTOP, 64, 0, stream>>>(points, topk, idx0, idx1, idx2);

    if (mfma_ok) {
        k_scale_mfma<16, 32, 32, 64><<<256, 256, 0, stream>>>(
            feat, points, topk, idx0,
            whi[0][0], wlo[0][0], whi[0][1], wlo[0][1], whi[0][2], wlo[0][2],
            s0_b0, s0_b1, s0_b2, feat_abs, pB, 0);
        k_scale_mfma<32, 64, 64, 128><<<512, 256, 0, stream>>>(
            feat, points, topk, idx1,
            whi[1][0], wlo[1][0], whi[1][1], wlo[1][1], whi[1][2], wlo[1][2],
            s1_b0, s1_b1, s1_b2, feat_abs, pB, 64);
        k_scale_mfma<128, 64, 96, 128><<<2048, 256, 0, stream>>>(
            feat, points, topk, idx2,
            whi[2][0], wlo[2][0], whi[2][1], wlo[2][1], whi[2][2], wlo[2][2],
            s2_b0, s2_b1, s2_b2, feat_abs, pB, 192);
    } else {
        k_scale<<<NB * KTOP, 256, 0, stream>>>(feat, points, topk, idx0, 16,
            s0_w0, s0_b0, 32, s0_w1, s0_b1, 32, s0_w2, s0_b2, 64, feat_abs, 0);
        k_scale<<<NB * KTOP, 256, 0, stream>>>(feat, points, topk, idx1, 32,
            s1_w0, s1_b0, 64, s1_w1, s1_b1, 64, s1_w2, s1_b2, 128, feat_abs, 64);
        k_scale<<<NB * KTOP, 256, 0, stream>>>(feat, points, topk, idx2, 128,
            s2_w0, s2_b0, 64, s2_w1, s2_b1, 96, s2_w2, s2_b2, 128, feat_abs, 192);
    }

    k_agg<<<NB * KTOP, 256, 0, stream>>>(feat_abs, pB, mfma_ok ? 1 : 0, score, topk, points,
        ag_w0, ag_b0, ag_w1, ag_b1, ag_w2, ag_b2, (float*)d_out);
}

// Round 7
// 759.265 us; speedup vs baseline: 1.3083x; 1.3083x over previous
//
#include <hip/hip_runtime.h>
#include <hip/hip_bf16.h>

#define NB 16
#define NPTS 4096
#define DM 512
#define KTOP 64

typedef float f32x4 __attribute__((ext_vector_type(4)));
typedef short s16x8 __attribute__((ext_vector_type(8)));

__device__ __forceinline__ unsigned short f2bf(float x) {
    unsigned u = __builtin_bit_cast(unsigned, x);
    unsigned r = (u + 0x7FFFu + ((u >> 16) & 1u)) >> 16;   // RNE
    return (unsigned short)r;
}
__device__ __forceinline__ float bf2f(unsigned short h) {
    return __builtin_bit_cast(float, (unsigned)h << 16);
}

// dual split: x ~= hi + lo (for scale MLPs, ~2^-17 rel)
__device__ __forceinline__ void buildFragP(const float* ap, s16x8& hi, s16x8& lo) {
    float4 u0 = *(const float4*)ap;
    float4 u1 = *(const float4*)(ap + 4);
    float xs[8] = {u0.x, u0.y, u0.z, u0.w, u1.x, u1.y, u1.z, u1.w};
    #pragma unroll
    for (int j = 0; j < 8; j++) {
        unsigned short h = f2bf(xs[j]);
        hi[j] = (short)h;
        lo[j] = (short)f2bf(xs[j] - bf2f(h));
    }
}

// triple split: x ~= hi + mi + lo (for score MLP, ~2^-27 rel)
__device__ __forceinline__ void buildFrag3(const float* ap, s16x8& hi, s16x8& mi, s16x8& lo) {
    float4 u0 = *(const float4*)ap;
    float4 u1 = *(const float4*)(ap + 4);
    float xs[8] = {u0.x, u0.y, u0.z, u0.w, u1.x, u1.y, u1.z, u1.w};
    #pragma unroll
    for (int j = 0; j < 8; j++) {
        unsigned short h = f2bf(xs[j]);
        float r = xs[j] - bf2f(h);           // exact
        unsigned short m = f2bf(r);
        float r2 = r - bf2f(m);              // exact
        hi[j] = (short)h;
        mi[j] = (short)m;
        lo[j] = (short)f2bf(r2);
    }
}

// ---------------- Kernel 0a: weight prep — transpose + dual split (scale MLPs) ----------------
struct PD { const float* w; unsigned short* hi; unsigned short* lo; int K, N, kpad; };
struct PA9 { PD d[9]; };

__global__ __launch_bounds__(256) void k_prep(PA9 p) {
    PD d = p.d[blockIdx.y];
    int total = d.N * d.kpad;
    for (int i = blockIdx.x * 256 + threadIdx.x; i < total; i += gridDim.x * 256) {
        int n = i / d.kpad, k = i - n * d.kpad;
        float x = (k < d.K) ? d.w[(long)k * d.N + n] : 0.f;
        unsigned short h = f2bf(x);
        d.hi[(long)n * d.kpad + k] = h;
        d.lo[(long)n * d.kpad + k] = f2bf(x - bf2f(h));
    }
}

// ---------------- Kernel 0b: weight prep — transpose + TRIPLE split (score MLP) ----------------
struct PD3 { const float* w; unsigned short* hi; unsigned short* mi; unsigned short* lo; int K, N, kpad; };
struct PA2 { PD3 d[2]; };

__global__ __launch_bounds__(256) void k_prep3(PA2 p) {
    PD3 d = p.d[blockIdx.y];
    int total = d.N * d.kpad;
    for (int i = blockIdx.x * 256 + threadIdx.x; i < total; i += gridDim.x * 256) {
        int n = i / d.kpad, k = i - n * d.kpad;
        float x = (k < d.K) ? d.w[(long)k * d.N + n] : 0.f;
        unsigned short h = f2bf(x);
        float r = x - bf2f(h);
        unsigned short m = f2bf(r);
        float r2 = r - bf2f(m);
        d.hi[(long)n * d.kpad + k] = h;
        d.mi[(long)n * d.kpad + k] = m;
        d.lo[(long)n * d.kpad + k] = f2bf(r2);
    }
}

// ---------------- Kernel 1a (MFMA GEMM): score layer1 512->256, triple-split x6 ----------------
// 512 blocks x 256thr. Block = M128 x N256. Wave = M64 x N128 quadrant: acc 4mt x 8ct.
// B chunks staged in LDS (shared by 4 waves, 24 MFMA per B-frag); A split from global in regs.
__global__ __launch_bounds__(256, 2) void k_fc1_mfma(
    const float* __restrict__ feat,
    const unsigned short* __restrict__ wh0, const unsigned short* __restrict__ wm0,
    const unsigned short* __restrict__ wl0,
    const float* __restrict__ b0,
    float* __restrict__ h1)
{
    constexpr int SWB = 40;                       // stride 40 shorts = 80 B: 16B-aligned, <=2-way conflicts
    __shared__ unsigned short sB[3][256 * SWB];   // 60 KB
    const int tid = threadIdx.x;
    const int lane = tid & 63, w = tid >> 6;
    const int q = lane >> 4, ln = lane & 15;
    const int wm = w & 1, wn = w >> 1;
    const long m0 = (long)blockIdx.x * 128 + wm * 64;

    f32x4 acc[4][8];
    #pragma unroll
    for (int mt = 0; mt < 4; mt++)
        #pragma unroll
        for (int ct = 0; ct < 8; ct++) acc[mt][ct] = (f32x4){0.f, 0.f, 0.f, 0.f};

    const unsigned short* wsplit[3] = {wh0, wm0, wl0};

    for (int kc = 0; kc < 16; kc++) {
        __syncthreads();
        #pragma unroll
        for (int s = 0; s < 3; s++) {
            const unsigned short* src = wsplit[s];
            #pragma unroll
            for (int c4 = 0; c4 < 4; c4++) {
                int c = tid + c4 * 256;           // 0..1023 chunks of 8 shorts
                int n = c >> 2, seg = (c & 3) * 8;
                *(float4*)&sB[s][n * SWB + seg] =
                    *(const float4*)(src + (long)n * 512 + kc * 32 + seg);
            }
        }
        __syncthreads();

        s16x8 ah[4], am[4], al[4];
        #pragma unroll
        for (int mt = 0; mt < 4; mt++)
            buildFrag3(feat + (m0 + mt * 16 + ln) * 512 + kc * 32 + q * 8, ah[mt], am[mt], al[mt]);

        #pragma unroll
        for (int ct = 0; ct < 8; ct++) {
            int nrow = (wn * 8 + ct) * 16 + ln;
            s16x8 bh = *(const s16x8*)&sB[0][nrow * SWB + q * 8];
            s16x8 bm = *(const s16x8*)&sB[1][nrow * SWB + q * 8];
            s16x8 bl = *(const s16x8*)&sB[2][nrow * SWB + q * 8];
            #pragma unroll
            for (int mt = 0; mt < 4; mt++) {
                acc[mt][ct] = __builtin_amdgcn_mfma_f32_16x16x32_bf16(ah[mt], bl, acc[mt][ct], 0, 0, 0);
                acc[mt][ct] = __builtin_amdgcn_mfma_f32_16x16x32_bf16(al[mt], bh, acc[mt][ct], 0, 0, 0);
                acc[mt][ct] = __builtin_amdgcn_mfma_f32_16x16x32_bf16(am[mt], bm, acc[mt][ct], 0, 0, 0);
                acc[mt][ct] = __builtin_amdgcn_mfma_f32_16x16x32_bf16(ah[mt], bm, acc[mt][ct], 0, 0, 0);
                acc[mt][ct] = __builtin_amdgcn_mfma_f32_16x16x32_bf16(am[mt], bh, acc[mt][ct], 0, 0, 0);
                acc[mt][ct] = __builtin_amdgcn_mfma_f32_16x16x32_bf16(ah[mt], bh, acc[mt][ct], 0, 0, 0);
            }
        }
    }
    #pragma unroll
    for (int ct = 0; ct < 8; ct++) {
        int col = (wn * 8 + ct) * 16 + ln;
        float bias = b0[col];
        #pragma unroll
        for (int mt = 0; mt < 4; mt++)
            #pragma unroll
            for (int r = 0; r < 4; r++)
                h1[(m0 + mt * 16 + 4 * q + r) * 256 + col] = fmaxf(acc[mt][ct][r] + bias, 0.f);
    }
}

// ---------------- Kernel 1b (MFMA): score layers 2+3 (256->64->1), triple-split ----------------
// 256 blocks x 256thr. Block = M256; wave = M64 x N64 (4mt x 4ct).
__global__ __launch_bounds__(256, 2) void k_fc23_mfma(
    const float* __restrict__ h1,
    const unsigned short* __restrict__ wh1, const unsigned short* __restrict__ wm1,
    const unsigned short* __restrict__ wl1,
    const float* __restrict__ b1,
    const float* __restrict__ w2, const float* __restrict__ b2,
    float* __restrict__ score)
{
    constexpr int SWB = 40;
    __shared__ __align__(16) char smem[256 * 68 * 4];   // h2[256][68] f32; overlays sB (15 KB)
    unsigned short* sB = (unsigned short*)smem;         // [3][64*SWB]
    const int tid = threadIdx.x;
    const int lane = tid & 63, w = tid >> 6;
    const int q = lane >> 4, ln = lane & 15;
    const long m0 = (long)blockIdx.x * 256 + w * 64;

    f32x4 acc[4][4];
    #pragma unroll
    for (int mt = 0; mt < 4; mt++)
        #pragma unroll
        for (int ct = 0; ct < 4; ct++) acc[mt][ct] = (f32x4){0.f, 0.f, 0.f, 0.f};

    const unsigned short* wsplit[3] = {wh1, wm1, wl1};

    for (int kc = 0; kc < 8; kc++) {
        __syncthreads();
        {
            int n = tid >> 2, seg = (tid & 3) * 8;      // 256 chunks cover 64 rows x 32 shorts
            #pragma unroll
            for (int s = 0; s < 3; s++)
                *(float4*)&sB[s * 64 * SWB + n * SWB + seg] =
                    *(const float4*)(wsplit[s] + (long)n * 256 + kc * 32 + seg);
        }
        __syncthreads();

        s16x8 ah[4], am[4], al[4];
        #pragma unroll
        for (int mt = 0; mt < 4; mt++)
            buildFrag3(h1 + (m0 + mt * 16 + ln) * 256 + kc * 32 + q * 8, ah[mt], am[mt], al[mt]);

        #pragma unroll
        for (int ct = 0; ct < 4; ct++) {
            int nrow = ct * 16 + ln;
            s16x8 bh = *(const s16x8*)&sB[0 * 64 * SWB + nrow * SWB + q * 8];
            s16x8 bm = *(const s16x8*)&sB[1 * 64 * SWB + nrow * SWB + q * 8];
            s16x8 bl = *(const s16x8*)&sB[2 * 64 * SWB + nrow * SWB + q * 8];
            #pragma unroll
            for (int mt = 0; mt < 4; mt++) {
                acc[mt][ct] = __builtin_amdgcn_mfma_f32_16x16x32_bf16(ah[mt], bl, acc[mt][ct], 0, 0, 0);
                acc[mt][ct] = __builtin_amdgcn_mfma_f32_16x16x32_bf16(al[mt], bh, acc[mt][ct], 0, 0, 0);
                acc[mt][ct] = __builtin_amdgcn_mfma_f32_16x16x32_bf16(am[mt], bm, acc[mt][ct], 0, 0, 0);
                acc[mt][ct] = __builtin_amdgcn_mfma_f32_16x16x32_bf16(ah[mt], bm, acc[mt][ct], 0, 0, 0);
                acc[mt][ct] = __builtin_amdgcn_mfma_f32_16x16x32_bf16(am[mt], bh, acc[mt][ct], 0, 0, 0);
                acc[mt][ct] = __builtin_amdgcn_mfma_f32_16x16x32_bf16(ah[mt], bh, acc[mt][ct], 0, 0, 0);
            }
        }
    }
    __syncthreads();                          // sB reads done before h2 overlay
    float* h2 = (float*)smem;                 // [256][68]
    #pragma unroll
    for (int ct = 0; ct < 4; ct++) {
        int col = ct * 16 + ln;
        float bias = b1[col];
        #pragma unroll
        for (int mt = 0; mt < 4; mt++)
            #pragma unroll
            for (int r = 0; r < 4; r++)
                h2[(w * 64 + mt * 16 + 4 * q + r) * 68 + col] = fmaxf(acc[mt][ct][r] + bias, 0.f);
    }
    __syncthreads();
    // layer 3: thread t -> row t (stride 17 dwords => conflict-free up to 2-way)
    float a3 = 0.f;
    #pragma unroll
    for (int i = 0; i < 64; i++) a3 += h2[tid * 68 + i] * w2[i];
    score[(long)blockIdx.x * 256 + tid] = a3 + b2[0];
}

// ---------------- (fallback) old score MLP ----------------
__global__ __launch_bounds__(256) void k_score(
    const float* __restrict__ feat,
    const float* __restrict__ w0, const float* __restrict__ b0,
    const float* __restrict__ w1, const float* __restrict__ b1,
    const float* __restrict__ w2, const float* __restrict__ b2,
    float* __restrict__ score)
{
    __shared__ float fbuf[16][512];
    __shared__ float h1[16][256];
    __shared__ float h2[16][64];
    const int tid = threadIdx.x;
    const long p0 = (long)blockIdx.x * 16;

    for (int e = tid; e < 16 * 512; e += 256) {
        int m = e >> 9, i = e & 511;
        fbuf[m][i] = feat[(p0 + m) * 512 + i];
    }
    __syncthreads();
    {
        const int o = tid;
        float acc[16];
        const float bb = b0[o];
        #pragma unroll
        for (int m = 0; m < 16; m++) acc[m] = bb;
        for (int i = 0; i < 512; i++) {
            float w = w0[i * 256 + o];
            #pragma unroll
            for (int m = 0; m < 16; m++) acc[m] += fbuf[m][i] * w;
        }
        #pragma unroll
        for (int m = 0; m < 16; m++) h1[m][o] = fmaxf(acc[m], 0.f);
    }
    __syncthreads();
    {
        const int o = tid & 63, g = tid >> 6;
        float acc[4];
        const float bb = b1[o];
        #pragma unroll
        for (int mm = 0; mm < 4; mm++) acc[mm] = bb;
        for (int i = 0; i < 256; i++) {
            float w = w1[i * 64 + o];
            #pragma unroll
            for (int mm = 0; mm < 4; mm++) acc[mm] += h1[g * 4 + mm][i] * w;
        }
        #pragma unroll
        for (int mm = 0; mm < 4; mm++) h2[g * 4 + mm][o] = fmaxf(acc[mm], 0.f);
    }
    __syncthreads();
    if (tid < 16) {
        float acc = b2[0];
        for (int i = 0; i < 64; i++) acc += h2[tid][i] * w2[i];
        score[p0 + tid] = acc;
    }
}

// ---------------- Kernel 2: top-64 per batch (desc, ties -> lower idx) ----------------
__global__ __launch_bounds__(256) void k_topk(const float* __restrict__ score,
                                              int* __restrict__ topk)
{
    __shared__ float sc[4096];
    __shared__ float wv[4];
    __shared__ int   wi[4];
    const int b = blockIdx.x, tid = threadIdx.x;
    const int lane = tid & 63, w = tid >> 6;
    for (int e = tid; e < 4096; e += 256) sc[e] = score[b * 4096 + e];
    __syncthreads();
    for (int it = 0; it < KTOP; it++) {
        float bv = -INFINITY; int bi = 1 << 30;
        #pragma unroll
        for (int j = 0; j < 16; j++) {
            int e = tid + 256 * j;
            float v = sc[e];
            if (v > bv || (v == bv && e < bi)) { bv = v; bi = e; }
        }
        #pragma unroll
        for (int s = 1; s < 64; s <<= 1) {
            float ov = __shfl_xor(bv, s);
            int   oi = __shfl_xor(bi, s);
            if (ov > bv || (ov == bv && oi < bi)) { bv = ov; bi = oi; }
        }
        if (lane == 0) { wv[w] = bv; wi[w] = bi; }
        __syncthreads();
        if (tid == 0) {
            float v = wv[0]; int i = wi[0];
            #pragma unroll
            for (int k = 1; k < 4; k++)
                if (wv[k] > v || (wv[k] == v && wi[k] < i)) { v = wv[k]; i = wi[k]; }
            topk[b * KTOP + it] = i;
            sc[i] = -INFINITY;
        }
        __syncthreads();
    }
}

// ---------------- Kernel 3: ball grouping (1 wave per (b,s)) ----------------
__global__ __launch_bounds__(64) void k_ball(
    const float* __restrict__ points, const int* __restrict__ topk,
    int* __restrict__ idx0, int* __restrict__ idx1, int* __restrict__ idx2)
{
    const int bs = blockIdx.x;
    const int b = bs >> 6;
    const int lane = threadIdx.x;
    const int j0 = topk[bs];
    const float* pb = points + (long)b * NPTS * 6;
    const float qx = pb[(long)j0 * 6 + 0];
    const float qy = pb[(long)j0 * 6 + 1];
    const float qz = pb[(long)j0 * 6 + 2];
    const float r2s[3] = {0.01f, 0.04f, 0.16f};
    const int ns[3] = {16, 32, 128};
    int cnt[3] = {0, 0, 0};
    int firstj[3] = {0, 0, 0};
    int* lists[3] = {idx0 + bs * 16, idx1 + bs * 32, idx2 + bs * 128};

    for (int c = 0; c < NPTS / 64; c++) {
        int j = c * 64 + lane;
        float px = pb[(long)j * 6 + 0];
        float py = pb[(long)j * 6 + 1];
        float pz = pb[(long)j * 6 + 2];
        float dx = __fsub_rn(qx, px), dy = __fsub_rn(qy, py), dz = __fsub_rn(qz, pz);
        float d2 = __fadd_rn(__fadd_rn(__fmul_rn(dx, dx), __fmul_rn(dy, dy)), __fmul_rn(dz, dz));
        #pragma unroll
        for (int r = 0; r < 3; r++) {
            bool inr = d2 <= r2s[r];
            unsigned long long m = __ballot(inr);
            if (m == 0ULL) continue;
            if (cnt[r] == 0) firstj[r] = c * 64 + (__ffsll((unsigned long long)m) - 1);
            if (cnt[r] < ns[r] && inr) {
                int pos = cnt[r] + __popcll(m & ((1ULL << lane) - 1ULL));
                if (pos < ns[r]) lists[r][pos] = j;
            }
            cnt[r] += __popcll(m);
        }
    }
    #pragma unroll
    for (int r = 0; r < 3; r++) {
        int filled = cnt[r] < ns[r] ? cnt[r] : ns[r];
        for (int p = filled + lane; p < ns[r]; p += 64) lists[r][p] = firstj[r];
    }
}

// ---------------- Kernel 4 (MFMA): per-scale grouped MLP + max, dual-split bf16 x3 ----------------
template<int NS, int C1, int C2, int C3>
__global__ __launch_bounds__(256) void k_scale_mfma(
    const float* __restrict__ feat, const float* __restrict__ points,
    const int* __restrict__ topk, const int* __restrict__ idxlist,
    const unsigned short* __restrict__ wh0, const unsigned short* __restrict__ wl0,
    const unsigned short* __restrict__ wh1, const unsigned short* __restrict__ wl1,
    const unsigned short* __restrict__ wh2, const unsigned short* __restrict__ wl2,
    const float* __restrict__ b0, const float* __restrict__ b1, const float* __restrict__ b2,
    float* __restrict__ pA, float* __restrict__ pB, int colOff)
{
    constexpr int KP1 = 544;
    constexpr int CMAX = C3;
    constexpr int SA = 100, SB = 72, SW = 40;
    __shared__ float bufA[64 * SA];
    __shared__ float bufB[64 * SB];
    __shared__ unsigned short wHi[CMAX * SW];
    __shared__ unsigned short wLo[CMAX * SW];

    const int tid = threadIdx.x;
    const int lane = tid & 63, w = tid >> 6;
    const int q = lane >> 4, ln = lane & 15;
    const int bblk = ((blockIdx.x * 64) / NS) >> 6;

    int* row_j = (int*)bufB;
    float* qv = bufB + 64;

    if (tid < 64) {
        int P = blockIdx.x * 64 + tid;
        int g = P / NS;
        int j = idxlist[P];
        row_j[tid] = j;
        int j0 = topk[g];
        const float* pp = points + ((long)bblk * NPTS + j0) * 6;
        qv[tid * 3 + 0] = pp[0];
        qv[tid * 3 + 1] = pp[1];
        qv[tid * 3 + 2] = pp[2];
    }
    __syncthreads();

    const float* fbase = feat + (long)bblk * NPTS * 512;
    const float* pbase = points + (long)bblk * NPTS * 6;

    f32x4 acc1[C1 / 16];
    #pragma unroll
    for (int t = 0; t < C1 / 16; t++) acc1[t] = (f32x4){0.f, 0.f, 0.f, 0.f};

    for (int kc = 0; kc < KP1 / 32; kc++) {
        {
            int row = tid >> 2, seg = tid & 3;
            int j = row_j[row];
            float4 v0, v1;
            if (kc < 16) {
                const float* src = fbase + (long)j * 512 + kc * 32 + seg * 8;
                v0 = *(const float4*)src;
                v1 = *(const float4*)(src + 4);
            } else {
                v0 = make_float4(0.f, 0.f, 0.f, 0.f);
                v1 = make_float4(0.f, 0.f, 0.f, 0.f);
                if (seg == 0) {
                    const float* pj = pbase + (long)j * 6;
                    v0.x = __fsub_rn(pj[0], qv[row * 3 + 0]);
                    v0.y = __fsub_rn(pj[1], qv[row * 3 + 1]);
                    v0.z = __fsub_rn(pj[2], qv[row * 3 + 2]);
                }
            }
            *(float4*)&bufA[row * SA + seg * 8] = v0;
            *(float4*)&bufA[row * SA + seg * 8 + 4] = v1;
        }
        for (int i = tid; i < C1 * 4; i += 256) {
            int n = i >> 2, seg = i & 3;
            long off = (long)n * KP1 + kc * 32 + seg * 8;
            *(float4*)&wHi[n * SW + seg * 8] = *(const float4*)(wh0 + off);
            *(float4*)&wLo[n * SW + seg * 8] = *(const float4*)(wl0 + off);
        }
        __syncthreads();

        s16x8 ahi, alo;
        buildFragP(&bufA[(16 * w + ln) * SA + q * 8], ahi, alo);
        #pragma unroll
        for (int ct = 0; ct < C1 / 16; ct++) {
            s16x8 bhi = *(const s16x8*)&wHi[(ct * 16 + ln) * SW + q * 8];
            s16x8 blo = *(const s16x8*)&wLo[(ct * 16 + ln) * SW + q * 8];
            acc1[ct] = __builtin_amdgcn_mfma_f32_16x16x32_bf16(ahi, bhi, acc1[ct], 0, 0, 0);
            acc1[ct] = __builtin_amdgcn_mfma_f32_16x16x32_bf16(ahi, blo, acc1[ct], 0, 0, 0);
            acc1[ct] = __builtin_amdgcn_mfma_f32_16x16x32_bf16(alo, bhi, acc1[ct], 0, 0, 0);
        }
        __syncthreads();
    }
    #pragma unroll
    for (int ct = 0; ct < C1 / 16; ct++) {
        float bias = b0[ct * 16 + ln];
        #pragma unroll
        for (int r = 0; r < 4; r++) {
            float v = fmaxf(acc1[ct][r] + bias, 0.f);
            bufB[(16 * w + 4 * q + r) * SB + ct * 16 + ln] = v;
        }
    }
    __syncthreads();

    f32x4 acc2[C2 / 16];
    #pragma unroll
    for (int t = 0; t < C2 / 16; t++) acc2[t] = (f32x4){0.f, 0.f, 0.f, 0.f};

    for (int kc = 0; kc < C1 / 32; kc++) {
        for (int i = tid; i < C2 * 4; i += 256) {
            int n = i >> 2, seg = i & 3;
            long off = (long)n * C1 + kc * 32 + seg * 8;
            *(float4*)&wHi[n * SW + seg * 8] = *(const float4*)(wh1 + off);
            *(float4*)&wLo[n * SW + seg * 8] = *(const float4*)(wl1 + off);
        }
        __syncthreads();
        s16x8 ahi, alo;
        buildFragP(&bufB[(16 * w + ln) * SB + kc * 32 + q * 8], ahi, alo);
        #pragma unroll
        for (int ct = 0; ct < C2 / 16; ct++) {
            s16x8 bhi = *(const s16x8*)&wHi[(ct * 16 + ln) * SW + q * 8];
            s16x8 blo = *(const s16x8*)&wLo[(ct * 16 + ln) * SW + q * 8];
            acc2[ct] = __builtin_amdgcn_mfma_f32_16x16x32_bf16(ahi, bhi, acc2[ct], 0, 0, 0);
            acc2[ct] = __builtin_amdgcn_mfma_f32_16x16x32_bf16(ahi, blo, acc2[ct], 0, 0, 0);
            acc2[ct] = __builtin_amdgcn_mfma_f32_16x16x32_bf16(alo, bhi, acc2[ct], 0, 0, 0);
        }
        __syncthreads();
    }
    #pragma unroll
    for (int ct = 0; ct < C2 / 16; ct++) {
        float bias = b1[ct * 16 + ln];
        #pragma unroll
        for (int r = 0; r < 4; r++) {
            float v = fmaxf(acc2[ct][r] + bias, 0.f);
            bufA[(16 * w + 4 * q + r) * SA + ct * 16 + ln] = v;
        }
    }
    __syncthreads();

    f32x4 acc3[C3 / 16];
    #pragma unroll
    for (int t = 0; t < C3 / 16; t++) acc3[t] = (f32x4){0.f, 0.f, 0.f, 0.f};

    for (int kc = 0; kc < C2 / 32; kc++) {
        for (int i = tid; i < C3 * 4; i += 256) {
            int n = i >> 2, seg = i & 3;
            long off = (long)n * C2 + kc * 32 + seg * 8;
            *(float4*)&wHi[n * SW + seg * 8] = *(const float4*)(wh2 + off);
            *(float4*)&wLo[n * SW + seg * 8] = *(const float4*)(wl2 + off);
        }
        __syncthreads();
        s16x8 ahi, alo;
        buildFragP(&bufA[(16 * w + ln) * SA + kc * 32 + q * 8], ahi, alo);
        #pragma unroll
        for (int ct = 0; ct < C3 / 16; ct++) {
            s16x8 bhi = *(const s16x8*)&wHi[(ct * 16 + ln) * SW + q * 8];
            s16x8 blo = *(const s16x8*)&wLo[(ct * 16 + ln) * SW + q * 8];
            acc3[ct] = __builtin_amdgcn_mfma_f32_16x16x32_bf16(ahi, bhi, acc3[ct], 0, 0, 0);
            acc3[ct] = __builtin_amdgcn_mfma_f32_16x16x32_bf16(ahi, blo, acc3[ct], 0, 0, 0);
            acc3[ct] = __builtin_amdgcn_mfma_f32_16x16x32_bf16(alo, bhi, acc3[ct], 0, 0, 0);
        }
        __syncthreads();
    }
    float* part = bufB;
    #pragma unroll
    for (int ct = 0; ct < C3 / 16; ct++) {
        float bias = b2[ct * 16 + ln];
        float v = -INFINITY;
        #pragma unroll
        for (int r = 0; r < 4; r++) v = fmaxf(v, fmaxf(acc3[ct][r] + bias, 0.f));
        v = fmaxf(v, __shfl_xor(v, 16));
        v = fmaxf(v, __shfl_xor(v, 32));
        if (lane < 16) part[w * C3 + ct * 16 + lane] = v;
    }
    __syncthreads();

    constexpr int NSB = NS < 64 ? NS : 64;
    constexpr int WPG = NSB / 16;
    constexpr int NOG = 4 / WPG;
    if (tid < NOG * C3) {
        int o = tid / C3, c = tid - o * C3;
        float v = part[(o * WPG) * C3 + c];
        #pragma unroll
        for (int i = 1; i < WPG; i++) v = fmaxf(v, part[(o * WPG + i) * C3 + c]);
        int g = (blockIdx.x * 64) / NS + o;
        if (NS <= 64) {
            pA[g * 320 + colOff + c] = v;
        } else {
            if ((blockIdx.x & 1) == 0) pA[g * 320 + colOff + c] = v;
            else pB[g * 128 + c] = v;
        }
    }
}

// ---------------- (fallback) old per-scale MLP ----------------
__global__ __launch_bounds__(256) void k_scale(
    const float* __restrict__ feat, const float* __restrict__ points,
    const int* __restrict__ topk, const int* __restrict__ idxlist, int ns,
    const float* __restrict__ w0, const float* __restrict__ b0, int C1,
    const float* __restrict__ w1, const float* __restrict__ b1, int C2,
    const float* __restrict__ w2, const float* __restrict__ b2, int C3,
    float* __restrict__ feat_abs, int colOff)
{
    __shared__ float g[2][520];
    __shared__ float h1[2][128];
    __shared__ float h2[2][128];
    const int bs = blockIdx.x;
    const int b = bs >> 6;
    const int tid = threadIdx.x;
    const int ks = tid >> 7;
    const int c = tid & 127;
    const int j0 = topk[bs];
    const float* pb = points + (long)b * NPTS * 6;
    const float* fb = feat + (long)b * NPTS * 512;
    const float q0 = pb[(long)j0 * 6 + 0];
    const float q1 = pb[(long)j0 * 6 + 1];
    const float q2 = pb[(long)j0 * 6 + 2];
    float omax = -INFINITY;
    const int* il = idxlist + bs * ns;

    for (int k0 = 0; k0 < ns; k0 += 2) {
        for (int kk = 0; kk < 2; kk++) {
            int j = il[k0 + kk];
            for (int e = tid; e < 512; e += 256) g[kk][e] = fb[(long)j * 512 + e];
            if (tid == 0) {
                g[kk][512] = __fsub_rn(pb[(long)j * 6 + 0], q0);
                g[kk][513] = __fsub_rn(pb[(long)j * 6 + 1], q1);
                g[kk][514] = __fsub_rn(pb[(long)j * 6 + 2], q2);
            }
        }
        __syncthreads();
        if (c < C1) {
            float acc = b0[c];
            for (int i = 0; i < 515; i++) acc += g[ks][i] * w0[i * C1 + c];
            h1[ks][c] = fmaxf(acc, 0.f);
        }
        __syncthreads();
        if (c < C2) {
            float acc = b1[c];
            for (int i = 0; i < C1; i++) acc += h1[ks][i] * w1[i * C2 + c];
            h2[ks][c] = fmaxf(acc, 0.f);
        }
        __syncthreads();
        if (c < C3) {
            float acc = b2[c];
            for (int i = 0; i < C2; i++) acc += h2[ks][i] * w2[i * C3 + c];
            omax = fmaxf(omax, fmaxf(acc, 0.f));
        }
        __syncthreads();
    }
    if (ks == 1 && c < C3) h1[0][c] = omax;
    __syncthreads();
    if (ks == 0 && c < C3)
        feat_abs[bs * 320 + colOff + c] = fmaxf(omax, h1[0][c]);
}

// ---------------- Kernel 5: agg MLP 320->256->256->505 + concat ----------------
__global__ __launch_bounds__(256) void k_agg(
    const float* __restrict__ feat_abs, const float* __restrict__ pB, int usePB,
    const float* __restrict__ score,
    const int* __restrict__ topk, const float* __restrict__ points,
    const float* __restrict__ w0, const float* __restrict__ b0,
    const float* __restrict__ w1, const float* __restrict__ b1,
    const float* __restrict__ w2, const float* __restrict__ b2,
    float* __restrict__ out)
{
    __shared__ float x[320];
    __shared__ float h1[256];
    __shared__ float h2[256];
    const int bs = blockIdx.x, tid = threadIdx.x;
    const int b = bs >> 6;
    for (int e = tid; e < 320; e += 256) {
        float v = feat_abs[bs * 320 + e];
        if (usePB && e >= 192) v = fmaxf(v, pB[bs * 128 + (e - 192)]);
        x[e] = v;
    }
    __syncthreads();
    {
        float acc = b0[tid];
        for (int i = 0; i < 320; i++) acc += x[i] * w0[i * 256 + tid];
        h1[tid] = fmaxf(acc, 0.f);
    }
    __syncthreads();
    {
        float acc = b1[tid];
        for (int i = 0; i < 256; i++) acc += h1[i] * w1[i * 256 + tid];
        h2[tid] = fmaxf(acc, 0.f);
    }
    __syncthreads();
    float* orow = out + (long)bs * 512;
    for (int o = tid; o < 505; o += 256) {
        float acc = b2[o];
        for (int i = 0; i < 256; i++) acc += h2[i] * w2[i * 505 + o];
        orow[o] = acc;
    }
    if (tid == 0) {
        int j = topk[bs];
        orow[505] = score[b * 4096 + j];
        #pragma unroll
        for (int d = 0; d < 6; d++) orow[506 + d] = points[((long)b * NPTS + j) * 6 + d];
    }
}

extern "C" void kernel_launch(void* const* d_in, const int* in_sizes, int n_in,
                              void* d_out, int out_size, void* d_ws, size_t ws_size,
                              hipStream_t stream)
{
    const float* points = (const float*)d_in[0];
    const float* feat   = (const float*)d_in[1];
    const float* fc_w0 = (const float*)d_in[2];  const float* fc_b0 = (const float*)d_in[3];
    const float* fc_w1 = (const float*)d_in[4];  const float* fc_b1 = (const float*)d_in[5];
    const float* fc_w2 = (const float*)d_in[6];  const float* fc_b2 = (const float*)d_in[7];
    const float* s0_w0 = (const float*)d_in[8];  const float* s0_b0 = (const float*)d_in[9];
    const float* s0_w1 = (const float*)d_in[10]; const float* s0_b1 = (const float*)d_in[11];
    const float* s0_w2 = (const float*)d_in[12]; const float* s0_b2 = (const float*)d_in[13];
    const float* s1_w0 = (const float*)d_in[14]; const float* s1_b0 = (const float*)d_in[15];
    const float* s1_w1 = (const float*)d_in[16]; const float* s1_b1 = (const float*)d_in[17];
    const float* s1_w2 = (const float*)d_in[18]; const float* s1_b2 = (const float*)d_in[19];
    const float* s2_w0 = (const float*)d_in[20]; const float* s2_b0 = (const float*)d_in[21];
    const float* s2_w1 = (const float*)d_in[22]; const float* s2_b1 = (const float*)d_in[23];
    const float* s2_w2 = (const float*)d_in[24]; const float* s2_b2 = (const float*)d_in[25];
    const float* ag_w0 = (const float*)d_in[26]; const float* ag_b0 = (const float*)d_in[27];
    const float* ag_w1 = (const float*)d_in[28]; const float* ag_b1 = (const float*)d_in[29];
    const float* ag_w2 = (const float*)d_in[30]; const float* ag_b2 = (const float*)d_in[31];

    char* ws = (char*)d_ws;
    float* score    = (float*)(ws + 0);
    int*   topk     = (int*)  (ws + 262144);
    int*   idx0     = (int*)  (ws + 266240);
    int*   idx1     = (int*)  (ws + 331776);
    int*   idx2     = (int*)  (ws + 462848);
    float* feat_abs = (float*)(ws + 987136);          // pA [1024][320]
    float* pB       = (float*)(ws + 2297856);         // [1024][128]
    size_t cur = 2822144;
    auto alloc = [&](size_t bytes) { size_t o = cur; cur = (cur + bytes + 255) & ~(size_t)255; return o; };

    const int Cs[3][3] = {{32, 32, 64}, {64, 64, 128}, {64, 96, 128}};
    const float* Wsrc[3][3] = {{s0_w0, s0_w1, s0_w2}, {s1_w0, s1_w1, s1_w2}, {s2_w0, s2_w1, s2_w2}};
    unsigned short* whi[3][3]; unsigned short* wlo[3][3];
    PA9 pargs;
    int di = 0;
    for (int s = 0; s < 3; s++) {
        int Ks[3] = {515, Cs[s][0], Cs[s][1]};
        int Kp[3] = {544, Cs[s][0], Cs[s][1]};
        for (int l = 0; l < 3; l++) {
            int N = Cs[s][l];
            size_t bytes = (size_t)N * Kp[l] * 2;
            whi[s][l] = (unsigned short*)(ws + alloc(bytes));
            wlo[s][l] = (unsigned short*)(ws + alloc(bytes));
            pargs.d[di++] = {Wsrc[s][l], whi[s][l], wlo[s][l], Ks[l], N, Kp[l]};
        }
    }
    // fc weights (triple split): fc_w0 [512][256] kpad=512, fc_w1 [256][64] kpad=256
    unsigned short* fhi0 = (unsigned short*)(ws + alloc((size_t)256 * 512 * 2));
    unsigned short* fmi0 = (unsigned short*)(ws + alloc((size_t)256 * 512 * 2));
    unsigned short* flo0 = (unsigned short*)(ws + alloc((size_t)256 * 512 * 2));
    unsigned short* fhi1 = (unsigned short*)(ws + alloc((size_t)64 * 256 * 2));
    unsigned short* fmi1 = (unsigned short*)(ws + alloc((size_t)64 * 256 * 2));
    unsigned short* flo1 = (unsigned short*)(ws + alloc((size_t)64 * 256 * 2));
    PA2 pargs3;
    pargs3.d[0] = {fc_w0, fhi0, fmi0, flo0, 512, 256, 512};
    pargs3.d[1] = {fc_w1, fhi1, fmi1, flo1, 256, 64, 256};

    // h1 activations for the two-stage score GEMM: [65536][256] f32 = 64 MB
    float* h1buf = (float*)(ws + alloc((size_t)65536 * 256 * 4));

    bool mfma_ok = (ws_size >= cur);

    if (mfma_ok) {
        k_prep<<<dim3(136, 9), 256, 0, stream>>>(pargs);
        k_prep3<<<dim3(512, 2), 256, 0, stream>>>(pargs3);
        k_fc1_mfma<<<512, 256, 0, stream>>>(feat, fhi0, fmi0, flo0, fc_b0, h1buf);
        k_fc23_mfma<<<256, 256, 0, stream>>>(h1buf, fhi1, fmi1, flo1, fc_b1, fc_w2, fc_b2, score);
    } else {
        k_score<<<4096, 256, 0, stream>>>(feat, fc_w0, fc_b0, fc_w1, fc_b1, fc_w2, fc_b2, score);
    }
    k_topk<<<NB, 256, 0, stream>>>(score, topk);
    k_ball<<<NB * KTOP, 64, 0, stream>>>(points, topk, idx0, idx1, idx2);

    if (mfma_ok) {
        k_scale_mfma<16, 32, 32, 64><<<256, 256, 0, stream>>>(
            feat, points, topk, idx0,
            whi[0][0], wlo[0][0], whi[0][1], wlo[0][1], whi[0][2], wlo[0][2],
            s0_b0, s0_b1, s0_b2, feat_abs, pB, 0);
        k_scale_mfma<32, 64, 64, 128><<<512, 256, 0, stream>>>(
            feat, points, topk, idx1,
            whi[1][0], wlo[1][0], whi[1][1], wlo[1][1], whi[1][2], wlo[1][2],
            s1_b0, s1_b1, s1_b2, feat_abs, pB, 64);
        k_scale_mfma<128, 64, 96, 128><<<2048, 256, 0, stream>>>(
            feat, points, topk, idx2,
            whi[2][0], wlo[2][0], whi[2][1], wlo[2][1], whi[2][2], wlo[2][2],
            s2_b0, s2_b1, s2_b2, feat_abs, pB, 192);
    } else {
        k_scale<<<NB * KTOP, 256, 0, stream>>>(feat, points, topk, idx0, 16,
            s0_w0, s0_b0, 32, s0_w1, s0_b1, 32, s0_w2, s0_b2, 64, feat_abs, 0);
        k_scale<<<NB * KTOP, 256, 0, stream>>>(feat, points, topk, idx1, 32,
            s1_w0, s1_b0, 64, s1_w1, s1_b1, 64, s1_w2, s1_b2, 128, feat_abs, 64);
        k_scale<<<NB * KTOP, 256, 0, stream>>>(feat, points, topk, idx2, 128,
            s2_w0, s2_b0, 64, s2_w1, s2_b1, 96, s2_w2, s2_b2, 128, feat_abs, 192);
    }

    k_agg<<<NB * KTOP, 256, 0, stream>>>(feat_abs, pB, mfma_ok ? 1 : 0, score, topk, points,
        ag_w0, ag_b0, ag_w1, ag_b1, ag_w2, ag_b2, (float*)d_out);
}